// Round 7
// baseline (261.317 us; speedup 1.0000x reference)
//
#include <hip/hip_runtime.h>
#include <math.h>

#define D_MODEL 1024
#define N_RES   2048
#define BATCH   32
#define NBLK    512
constexpr float INV_2PI = 0.15915494309189535f;

// ws layout (floats):
#define WS_XC  0                        // [32][1024]
#define WS_CS  (WS_XC + 32 * 1024)      // [32][2048]
#define WS_SS  (WS_CS + 32 * 2048)      // [32][2048]
#define WS_BAR (WS_SS + 32 * 2048)      // 2 uints: counter, generation

__device__ __forceinline__ float silu(float v) { return v / (1.f + __expf(-v)); }

// Sense-reversing grid barrier. Device-scope atomics + agent fences (per-XCD
// L2s are not coherent -> fences force L2 writeback/invalidate). Only lane 0
// of the block spins. Co-residency: 512 blocks at launch_bounds(256,4) =
// half of the 1024-block capacity -> all blocks resident at dispatch.
// (R5: hipLaunchCooperativeKernel at exactly-capacity 1024 blocks silently
// rejected -> zeros. R6: __hip_atomic_thread_fence doesn't exist in these
// headers; use __builtin_amdgcn_fence(ord,"agent") instead.)
__device__ __forceinline__ void grid_barrier(unsigned* bar) {
  __syncthreads();
  if (threadIdx.x == 0) {
    unsigned gen = __hip_atomic_load(&bar[1], __ATOMIC_RELAXED, __HIP_MEMORY_SCOPE_AGENT);
    __builtin_amdgcn_fence(__ATOMIC_RELEASE, "agent");
    unsigned arrived = __hip_atomic_fetch_add(&bar[0], 1u, __ATOMIC_ACQ_REL,
                                              __HIP_MEMORY_SCOPE_AGENT);
    if (arrived == NBLK - 1) {
      __hip_atomic_store(&bar[0], 0u, __ATOMIC_RELAXED, __HIP_MEMORY_SCOPE_AGENT);
      __hip_atomic_store(&bar[1], gen + 1u, __ATOMIC_RELEASE, __HIP_MEMORY_SCOPE_AGENT);
    } else {
      while (__hip_atomic_load(&bar[1], __ATOMIC_ACQUIRE, __HIP_MEMORY_SCOPE_AGENT) == gen) {
        __builtin_amdgcn_s_sleep(1);
      }
    }
    __builtin_amdgcn_fence(__ATOMIC_ACQUIRE, "agent");
  }
  __syncthreads();
}

// ---------------------------------------------------------------------------
// Fused 3-phase kernel, 512 blocks x 256 threads, one dispatch.
//  A: xc[b][d] = [xr|xi][b] . ipw[d] + bias[d]   (2 d per block, full K)
//  B: cs/ss[b][n] = sum_d cos/sin(2pi*(xc*a + c + t2))  (4 n per block)
//  C: out = silu(cs @ orw^T), silu(ss @ oiw^T)   (4 d x 1 comp per block)
// ---------------------------------------------------------------------------
__global__ __launch_bounds__(256, 4) void fused(const float* __restrict__ xr,
                                                const float* __restrict__ xi,
                                                const float* __restrict__ t,
                                                const float* __restrict__ ipw,
                                                const float* __restrict__ bias,
                                                const float* __restrict__ W,
                                                const float* __restrict__ Bm,
                                                const float* __restrict__ orw,
                                                const float* __restrict__ oiw,
                                                float* __restrict__ out,
                                                float* __restrict__ ws) {
  const int tid  = threadIdx.x;
  const int lane = tid & 63;
  const int wave = tid >> 6;
  const int b0   = wave * 8;

  float* xc = ws + WS_XC;
  float* cs = ws + WS_CS;
  float* ss = ws + WS_SS;
  unsigned* bar = (unsigned*)(ws + WS_BAR);

  // ---------------- Phase A: input GEMM, 2 d's per block, full K ----------
  {
    const int d0 = blockIdx.x * 2;
    const float4* xr4  = (const float4*)xr;   // 256 f4/row
    const float4* xi4  = (const float4*)xi;
    const float4* ipw4 = (const float4*)ipw;  // 512 f4/row

    float acc[8][2];
#pragma unroll
    for (int b = 0; b < 8; ++b) { acc[b][0] = 0.f; acc[b][1] = 0.f; }

#pragma unroll 1
    for (int i = 0; i < 4; ++i) {  // real half, k in [0,1024)
      const int j = lane + 64 * i;
      float4 w0 = ipw4[(size_t)d0 * 512 + j];
      float4 w1 = ipw4[(size_t)(d0 + 1) * 512 + j];
#pragma unroll
      for (int b = 0; b < 8; ++b) {
        float4 x4 = xr4[(b0 + b) * 256 + j];
        acc[b][0] += x4.x * w0.x + x4.y * w0.y + x4.z * w0.z + x4.w * w0.w;
        acc[b][1] += x4.x * w1.x + x4.y * w1.y + x4.z * w1.z + x4.w * w1.w;
      }
    }
#pragma unroll 1
    for (int i = 0; i < 4; ++i) {  // imag half, k in [1024,2048)
      const int j = lane + 64 * i;
      float4 w0 = ipw4[(size_t)d0 * 512 + 256 + j];
      float4 w1 = ipw4[(size_t)(d0 + 1) * 512 + 256 + j];
#pragma unroll
      for (int b = 0; b < 8; ++b) {
        float4 x4 = xi4[(b0 + b) * 256 + j];
        acc[b][0] += x4.x * w0.x + x4.y * w0.y + x4.z * w0.z + x4.w * w0.w;
        acc[b][1] += x4.x * w1.x + x4.y * w1.y + x4.z * w1.z + x4.w * w1.w;
      }
    }

#pragma unroll
    for (int b = 0; b < 8; ++b) {
#pragma unroll
      for (int d = 0; d < 2; ++d) {
        float v = acc[b][d];
#pragma unroll
        for (int m = 32; m >= 1; m >>= 1) v += __shfl_xor(v, m, 64);
        if (lane == 0) xc[(size_t)(b0 + b) * D_MODEL + d0 + d] = v + bias[d0 + d];
      }
    }
  }
  grid_barrier(bar);

  // ---------------- Phase B: sin/cos sums, 4 n's per block ----------------
#pragma unroll 1
  for (int nn = 0; nn < 4; ++nn) {
    const int n = (blockIdx.x << 2) | nn;
    const float4* W4 = (const float4*)(W + (size_t)n * D_MODEL);
    const float4* B4 = (const float4*)(Bm + (size_t)n * D_MODEL);
    float4 av[4], cv[4];
#pragma unroll
    for (int i = 0; i < 4; ++i) {
      float4 w4 = W4[lane + 64 * i];
      float4 b4 = B4[lane + 64 * i];
      av[i].x = INV_2PI / (1.f + fabsf(w4.x));
      av[i].y = INV_2PI / (1.f + fabsf(w4.y));
      av[i].z = INV_2PI / (1.f + fabsf(w4.z));
      av[i].w = INV_2PI / (1.f + fabsf(w4.w));
      cv[i].x = b4.x * INV_2PI;
      cv[i].y = b4.y * INV_2PI;
      cv[i].z = b4.z * INV_2PI;
      cv[i].w = b4.w * INV_2PI;
    }

#pragma unroll 1
    for (int bb = 0; bb < 8; ++bb) {
      const int b = b0 + bb;
      const float t2 = t[b] * INV_2PI;
      const float4* x4p = (const float4*)(xc + (size_t)b * D_MODEL);
      float ss0 = 0.f, ss1 = 0.f, cc0 = 0.f, cc1 = 0.f;
#pragma unroll
      for (int i = 0; i < 4; ++i) {
        float4 x4 = x4p[lane + 64 * i];
        float4 a4 = av[i];
        float4 c4 = cv[i];
        {
          float r = __builtin_amdgcn_fractf(x4.x * a4.x + c4.x + t2);
          ss0 += __builtin_amdgcn_sinf(r);
          cc0 += __builtin_amdgcn_cosf(r);
        }
        {
          float r = __builtin_amdgcn_fractf(x4.y * a4.y + c4.y + t2);
          ss1 += __builtin_amdgcn_sinf(r);
          cc1 += __builtin_amdgcn_cosf(r);
        }
        {
          float r = __builtin_amdgcn_fractf(x4.z * a4.z + c4.z + t2);
          ss0 += __builtin_amdgcn_sinf(r);
          cc0 += __builtin_amdgcn_cosf(r);
        }
        {
          float r = __builtin_amdgcn_fractf(x4.w * a4.w + c4.w + t2);
          ss1 += __builtin_amdgcn_sinf(r);
          cc1 += __builtin_amdgcn_cosf(r);
        }
      }
      float sv = ss0 + ss1;
      float cv2 = cc0 + cc1;
#pragma unroll
      for (int m = 32; m >= 1; m >>= 1) {
        sv  += __shfl_xor(sv, m, 64);
        cv2 += __shfl_xor(cv2, m, 64);
      }
      if (lane == 0) {
        cs[(size_t)b * N_RES + n] = cv2;
        ss[(size_t)b * N_RES + n] = sv;
      }
    }
  }
  grid_barrier(bar);

  // ---------------- Phase C: output GEMM + silu, full K ----------------
  // blockIdx = dtile(256) | comp<<8. comp 0: real (cs@orw), 1: imag (ss@oiw).
  {
    const int dtile = blockIdx.x & 255;
    const int comp  = blockIdx.x >> 8;
    const int d0    = dtile * 4;
    const float* src = comp ? ss : cs;    // [32][2048]
    const float* wm  = comp ? oiw : orw;  // [1024][2048]

    float acc[8][4];
#pragma unroll
    for (int b = 0; b < 8; ++b)
#pragma unroll
      for (int d = 0; d < 4; ++d) acc[b][d] = 0.f;

#pragma unroll 1
    for (int i = 0; i < 8; ++i) {
      const int j = lane + 64 * i;  // f4 idx over n in [0,512)
      float4 w4[4];
#pragma unroll
      for (int d = 0; d < 4; ++d) w4[d] = ((const float4*)(wm + (size_t)(d0 + d) * N_RES))[j];
#pragma unroll
      for (int b = 0; b < 8; ++b) {
        float4 s4 = ((const float4*)(src + (size_t)(b0 + b) * N_RES))[j];
#pragma unroll
        for (int d = 0; d < 4; ++d) {
          acc[b][d] += s4.x * w4[d].x + s4.y * w4[d].y + s4.z * w4[d].z + s4.w * w4[d].w;
        }
      }
    }

#pragma unroll
    for (int b = 0; b < 8; ++b) {
#pragma unroll
      for (int d = 0; d < 4; ++d) {
        float v = acc[b][d];
#pragma unroll
        for (int m = 32; m >= 1; m >>= 1) v += __shfl_xor(v, m, 64);
        if (lane == 0) {
          out[(size_t)comp * BATCH * D_MODEL + (size_t)(b0 + b) * D_MODEL + d0 + d] = silu(v);
        }
      }
    }
  }
}

extern "C" void kernel_launch(void* const* d_in, const int* in_sizes, int n_in,
                              void* d_out, int out_size, void* d_ws, size_t ws_size,
                              hipStream_t stream) {
  const float* xr   = (const float*)d_in[0];
  const float* xi   = (const float*)d_in[1];
  const float* t    = (const float*)d_in[2];
  const float* ipw  = (const float*)d_in[3];
  const float* bias = (const float*)d_in[4];
  const float* W    = (const float*)d_in[5];
  const float* Bm   = (const float*)d_in[6];
  const float* orw  = (const float*)d_in[7];
  const float* oiw  = (const float*)d_in[8];
  float* out = (float*)d_out;
  float* ws  = (float*)d_ws;

  // zero the barrier state (ws is re-poisoned to 0xAA before every launch)
  (void)hipMemsetAsync(ws + WS_BAR, 0, 2 * sizeof(unsigned), stream);

  fused<<<NBLK, 256, 0, stream>>>(xr, xi, t, ipw, bias, W, Bm, orw, oiw, out, ws);
}